// Round 1
// baseline (229.362 us; speedup 1.0000x reference)
//
#include <hip/hip_runtime.h>
#include <hip/hip_bf16.h>

// ConvIntrinsic: gather+barycentric -> patch-operator -> 8 rotated folds.
// Circular-correlation FFT formulation (R8, verified): 8-pt real DFT over
// the angular index on both sides; ĉ[k]=X*[k]Y[k] per bin k={0&4,1,2,3};
// inverse DFT + bias + relu + k-pair fold give the 8 rotation outputs.
//
// R10: GEMM de-LDS'd on the A side. rocprof R9: MfmaUtil 18.8 / VALU 17.2 /
// HBM 13.6% -> accounting shows LDS moved 52 KB per block-K-step (A write
// 16 + B write 4 + reads 32) = 74 B/cyc/CU ~ 87% of the 85 B/cyc b128
// ceiling: LDS-BW-bound. A has ZERO cross-wave reuse (each wave reads back
// its own staged rows), so A-frags now load global->VGPR directly (L2-
// resident slab, coalesced 16 rows x 64B), double-buffered across K-steps.
// B keeps its 4x inter-wave reuse through LDS (global_load_lds, pre-swizzled
// source), now double-buffered Bs0/Bs1 with ONE barrier per K-step and
// cross-bin prefetch. LDS traffic 52 -> 20 KB per block-K-step.

#define N_PTS 6000
#define RR 5
#define AA 8
#define FF 128
#define OO 128
#define QQ 40            // R*A
#define KD2 1280         // per-bin GEMM K: 5 rho x 2 part x 128 f
#define SIG_BLOCKS 750   // 8 points per block
#define W2_BLOCKS 128    // 2 j per block
#define CCQ 0.70710678118654752f
#define RT2 1.41421356237309515f

#define AHS ((size_t)N_PTS * KD2)  // per-bin Ahat elems
#define BHS ((size_t)512 * KD2)    // per-bin Bhat elems

typedef __bf16 bf16_t;
typedef __bf16 bf16x4 __attribute__((ext_vector_type(4)));
typedef __bf16 bf16x8 __attribute__((ext_vector_type(8)));
typedef float f32x4 __attribute__((ext_vector_type(4)));

#define GLOAD_LDS16(g, l)                                              \
  __builtin_amdgcn_global_load_lds(                                    \
      (const __attribute__((address_space(1))) void*)(g),              \
      (__attribute__((address_space(3))) void*)(l), 16, 0, 0)

// 8-point real DFT, X[k] = sum_a x[a] e^{-2pi i k a/8} (verified R8).
#define DFT8V(xx, c, X0, X4, Xr1, Xi1, Xr2, Xi2, Xr3, Xi3)             \
  {                                                                    \
    const float s0_ = xx[0][c] + xx[4][c], s1_ = xx[1][c] + xx[5][c];  \
    const float s2_ = xx[2][c] + xx[6][c], s3_ = xx[3][c] + xx[7][c];  \
    const float d0_ = xx[0][c] - xx[4][c], d1_ = xx[1][c] - xx[5][c];  \
    const float d2_ = xx[2][c] - xx[6][c], d3_ = xx[3][c] - xx[7][c];  \
    const float e_ = CCQ * (d1_ - d3_), o_ = CCQ * (d1_ + d3_);        \
    X0 = (s0_ + s2_) + (s1_ + s3_);                                    \
    X4 = (s0_ + s2_) - (s1_ + s3_);                                    \
    Xr2 = s0_ - s2_; Xi2 = s3_ - s1_;                                  \
    Xr1 = d0_ + e_;  Xi1 = -(o_ + d2_);                                \
    Xr3 = d0_ - e_;  Xi3 = d2_ - o_;                                   \
  }

#define PACK4(dst, X)                                                  \
  {                                                                    \
    bf16x4 pv_;                                                        \
    pv_[0] = (bf16_t)X[0]; pv_[1] = (bf16_t)X[1];                      \
    pv_[2] = (bf16_t)X[2]; pv_[3] = (bf16_t)X[3];                      \
    *(bf16x4*)(dst) = pv_;                                             \
  }

// ------------------------------------------------------- FFT prep pass
// blocks [0,750): 8 points each; 256 thr = 8 point-slots x 32 f4-lanes.
//   Register-direct: gather 24 float4 per (point,rho), DFT8 per f-comp,
//   8 packed bf16x4 stores into the 4 bins. No LDS, no barriers.
// blocks [750,878): Bhat (rot=0 cols) -> DFT -> 4 bins (x 1/8 norm).
__global__ __launch_bounds__(256) void prep_fft_kernel(
    const float* __restrict__ mesh, const float* __restrict__ bary,
    const float* __restrict__ kw, const float* __restrict__ interp,
    bf16_t* __restrict__ Ahat, bf16_t* __restrict__ Bhat) {
  __shared__ float sI[RR * AA * QQ];  // w2 branch only
  const int bx = blockIdx.x;
  const int tid = threadIdx.x;

  if (bx < SIG_BLOCKS) {
    const int slot = tid >> 5;  // 0..7
    const int l = tid & 31;     // f = l*4
    const int n = bx * 8 + slot;
    const float* bn = bary + (size_t)n * (QQ * 6);
    bf16_t* an = Ahat + (size_t)n * KD2 + l * 4;
#pragma unroll
    for (int rho = 0; rho < RR; ++rho) {
      float x[8][4];
#pragma unroll
      for (int a = 0; a < 8; ++a) {
        const float* b = bn + (rho * 8 + a) * 6;  // uniform in 32-lane group
        const float2 p0 = *(const float2*)(b);
        const float2 p1 = *(const float2*)(b + 2);
        const float2 p2 = *(const float2*)(b + 4);
        const float4 v0 =
            *(const float4*)(mesh + (size_t)((int)p0.x) * FF + l * 4);
        const float4 v1 =
            *(const float4*)(mesh + (size_t)((int)p1.x) * FF + l * 4);
        const float4 v2 =
            *(const float4*)(mesh + (size_t)((int)p2.x) * FF + l * 4);
        x[a][0] = p0.y * v0.x + p1.y * v1.x + p2.y * v2.x;
        x[a][1] = p0.y * v0.y + p1.y * v1.y + p2.y * v2.y;
        x[a][2] = p0.y * v0.z + p1.y * v1.z + p2.y * v2.z;
        x[a][3] = p0.y * v0.w + p1.y * v1.w + p2.y * v2.w;
      }
      float X0[4], X4[4], Xr1[4], Xi1[4], Xr2[4], Xi2[4], Xr3[4], Xi3[4];
#pragma unroll
      for (int c = 0; c < 4; ++c)
        DFT8V(x, c, X0[c], X4[c], Xr1[c], Xi1[c], Xr2[c], Xi2[c], Xr3[c],
              Xi3[c]);
      bf16_t* dst = an + rho * 256;
      PACK4(dst, X0);                  PACK4(dst + 128, X4);
      PACK4(dst + AHS, Xr1);           PACK4(dst + AHS + 128, Xi1);
      PACK4(dst + 2 * AHS, Xr2);       PACK4(dst + 2 * AHS + 128, Xi2);
      PACK4(dst + 3 * AHS, Xr3);       PACK4(dst + 3 * AHS + 128, Xi3);
    }
  } else {
    // ---- B side: two j columns per block (128 threads each).
    const int j = (bx - SIG_BLOCKS) * 2 + (tid >> 7);  // 0..255
    const int f = tid & 127;
    for (int i = tid; i < RR * AA * QQ; i += 256) sI[i] = interp[i];
    __syncthreads();
    const int o = (j >> 1) & 127;
    const int k = j & 1;
    float acc[QQ];
#pragma unroll
    for (int q = 0; q < QQ; ++q) acc[q] = 0.f;
    for (int r = 0; r < RR; ++r) {
      for (int a = 0; a < AA; ++a) {
        const float kv =
            kw[((size_t)((r * AA + a) * 2 + k) * OO + o) * FF + f];
        const float4* ip = (const float4*)(sI + (r * AA + a) * QQ);
#pragma unroll
        for (int q4 = 0; q4 < QQ / 4; ++q4) {
          const float4 w4 = ip[q4];
          acc[q4 * 4 + 0] += w4.x * kv;
          acc[q4 * 4 + 1] += w4.y * kv;
          acc[q4 * 4 + 2] += w4.z * kv;
          acc[q4 * 4 + 3] += w4.w * kv;
        }
      }
    }
    // DFT over a; 1/8 normalization folded in. Col j = Re-type, 256+j =
    // Im-type (bin0 packs Z0/Z4 there; bins 1-3 pack [Yr|Yi]/[Yi|-Yr]).
    const float SC = 0.125f;
    bf16_t* b1p = Bhat + (size_t)j * KD2 + f;
    bf16_t* b2p = Bhat + (size_t)(256 + j) * KD2 + f;
#pragma unroll
    for (int rho = 0; rho < RR; ++rho) {
      float xx[8][1];
#pragma unroll
      for (int a = 0; a < 8; ++a) xx[a][0] = acc[rho * 8 + a];
      float Y0, Y4, Yr1, Yi1, Yr2, Yi2, Yr3, Yi3;
      DFT8V(xx, 0, Y0, Y4, Yr1, Yi1, Yr2, Yi2, Yr3, Yi3);
      const int off = rho * 256;
      b1p[off] = (bf16_t)(Y0 * SC);        b1p[off + 128] = (bf16_t)0.f;
      b2p[off] = (bf16_t)0.f;              b2p[off + 128] = (bf16_t)(Y4 * SC);
      b1p[BHS + off] = (bf16_t)(Yr1 * SC);
      b1p[BHS + off + 128] = (bf16_t)(Yi1 * SC);
      b2p[BHS + off] = (bf16_t)(Yi1 * SC);
      b2p[BHS + off + 128] = (bf16_t)(-Yr1 * SC);
      b1p[2 * BHS + off] = (bf16_t)(Yr2 * SC);
      b1p[2 * BHS + off + 128] = (bf16_t)(Yi2 * SC);
      b2p[2 * BHS + off] = (bf16_t)(Yi2 * SC);
      b2p[2 * BHS + off + 128] = (bf16_t)(-Yr2 * SC);
      b1p[3 * BHS + off] = (bf16_t)(Yr3 * SC);
      b1p[3 * BHS + off + 128] = (bf16_t)(Yi3 * SC);
      b2p[3 * BHS + off] = (bf16_t)(Yi3 * SC);
      b2p[3 * BHS + off + 128] = (bf16_t)(-Yr3 * SC);
    }
  }
}

// --------------------------------------- fused GEMM + iDFT + epilogue
// Grid 768: xcd=L&7, t=L>>3; slab g=xcd+8*(t>>4) (0..47), j-tile jt=t&15.
// Block = 128m x 16j. A-frags: register-direct from global (no LDS round
// trip; zero cross-wave reuse), double-buffered aA/aB across K-steps.
// B tile (32 cols: rows 0-15 Re Z, 16-31 Im Z): LDS Bs0/Bs1 double-buffer
// via global_load_lds with pre-swizzled source; ONE barrier per K-step.
// Bins loop sequentially; per-bin iDFT fold into 8-rot accumulator, then
// bias+relu+shfl k-fold epilogue (verified R1-R9).
__global__ __launch_bounds__(256, 3) void gemm_fused_fft_kernel(
    const bf16_t* __restrict__ Ahat, const bf16_t* __restrict__ Bhat,
    const float* __restrict__ bias, float* __restrict__ out) {
  const int L = blockIdx.x;
  const int xcd = L & 7;
  const int t = L >> 3;                // 0..95
  const int g = xcd + 8 * (t >> 4);    // 0..47
  const int jt = t & 15;
  const int m0 = g * 128;
  if (m0 >= N_PTS) return;
  const int j0 = jt * 16;

  __shared__ bf16_t Bs0[32 * 64];
  __shared__ bf16_t Bs1[32 * 64];
  const int tid = threadIdx.x;
  const int wave = tid >> 6;
  const int lane = tid & 63;
  const int quad = lane >> 4;
  const int tl = lane & 15;
  const int wm = wave * 32;
  const int srow = lane >> 3;
  const int sc = (lane & 7) ^ srow;

  // this wave's B staging chunk (8 rows of the 32-row B tile)
  const int crow = wave * 8;
  const int colbase = (crow < 16) ? (j0 + crow) : (256 + j0 + (crow - 16));
  const size_t bcol = (size_t)(colbase + srow) * KD2 + sc * 8;

  // per-lane A row byte offsets for the two m-fragments (clamped tail)
  int r0 = m0 + wm + tl;       r0 = r0 < N_PTS ? r0 : (N_PTS - 1);
  int r1 = m0 + wm + 16 + tl;  r1 = r1 < N_PTS ? r1 : (N_PTS - 1);
  const size_t ro0 = (size_t)r0 * KD2 + quad * 8;
  const size_t ro1 = (size_t)r1 * KD2 + quad * 8;

  // iDFT coefficients: c_rot = sum_b cf[b][rot]*ReZ_b + sf[b][rot]*ImZ_b
  // (bin0: ReZ=Z0 cf=1, ImZ=Z4 sf=(-1)^rot). Verified in R8.
  static const float CF[4][8] = {
      {1, 1, 1, 1, 1, 1, 1, 1},
      {2, RT2, 0, -RT2, -2, -RT2, 0, RT2},
      {2, 0, -2, 0, 2, 0, -2, 0},
      {2, -RT2, 0, RT2, -2, RT2, 0, -RT2}};
  static const float SF[4][8] = {
      {1, -1, 1, -1, 1, -1, 1, -1},
      {0, -RT2, -2, -RT2, 0, RT2, 2, RT2},
      {0, -2, 0, 2, 0, -2, 0, 2},
      {0, -RT2, 2, -RT2, 0, RT2, -2, RT2}};

  f32x4 oacc[8][2];
#pragma unroll
  for (int rot = 0; rot < 8; ++rot)
#pragma unroll
    for (int mm = 0; mm < 2; ++mm) oacc[rot][mm] = {0.f, 0.f, 0.f, 0.f};

#define STAGE_B(Bp, kkv, bufn) \
  GLOAD_LDS16((Bp) + bcol + (kkv), Bs##bufn + crow * 64)

#define LOAD_A(p0, p1, p2, p3, Ap, kkv)                   \
  p0 = *(const bf16x8*)((Ap) + ro0 + (kkv));              \
  p1 = *(const bf16x8*)((Ap) + ro1 + (kkv));              \
  p2 = *(const bf16x8*)((Ap) + ro0 + (kkv) + 32);         \
  p3 = *(const bf16x8*)((Ap) + ro1 + (kkv) + 32);

  // p0/p1 = ks0 (K 0..31), p2/p3 = ks1 (K 32..63); b-read swizzle matches
  // the pre-swizzled staging source (rule #21 both-sides pair).
#define COMPUTE(Bsx, p0, p1, p2, p3)                                        \
  {                                                                         \
    const int ch0 = (quad ^ (tl & 7)) * 8;                                  \
    const int ch1 = ((4 + quad) ^ (tl & 7)) * 8;                            \
    bf16x8 b0 = *(const bf16x8*)(Bsx + tl * 64 + ch0);                      \
    bf16x8 b1 = *(const bf16x8*)(Bsx + (16 + tl) * 64 + ch0);               \
    z00 = __builtin_amdgcn_mfma_f32_16x16x32_bf16(p0, b0, z00, 0, 0, 0);    \
    z01 = __builtin_amdgcn_mfma_f32_16x16x32_bf16(p0, b1, z01, 0, 0, 0);    \
    z10 = __builtin_amdgcn_mfma_f32_16x16x32_bf16(p1, b0, z10, 0, 0, 0);    \
    z11 = __builtin_amdgcn_mfma_f32_16x16x32_bf16(p1, b1, z11, 0, 0, 0);    \
    b0 = *(const bf16x8*)(Bsx + tl * 64 + ch1);                             \
    b1 = *(const bf16x8*)(Bsx + (16 + tl) * 64 + ch1);                      \
    z00 = __builtin_amdgcn_mfma_f32_16x16x32_bf16(p2, b0, z00, 0, 0, 0);    \
    z01 = __builtin_amdgcn_mfma_f32_16x16x32_bf16(p2, b1, z01, 0, 0, 0);    \
    z10 = __builtin_amdgcn_mfma_f32_16x16x32_bf16(p3, b0, z10, 0, 0, 0);    \
    z11 = __builtin_amdgcn_mfma_f32_16x16x32_bf16(p3, b1, z11, 0, 0, 0);    \
  }

  bf16x8 aA0, aA1, aA2, aA3, aB0, aB1, aB2, aB3;
  f32x4 z00, z01, z10, z11;

  const bf16_t* A = Ahat;
  const bf16_t* B = Bhat;
  // prologue: bin0 kk=0 into Bs0 / aA
  STAGE_B(B, 0, 0);
  LOAD_A(aA0, aA1, aA2, aA3, A, 0);
  __syncthreads();

#pragma unroll
  for (int b = 0; b < 4; ++b) {
    z00 = {0.f, 0.f, 0.f, 0.f};
    z01 = {0.f, 0.f, 0.f, 0.f};
    z10 = {0.f, 0.f, 0.f, 0.f};
    z11 = {0.f, 0.f, 0.f, 0.f};
    int kk = 0;
#pragma unroll 1
    for (int d = 0; d < 9; ++d) {  // computes kk, kk+64; stages +64, +128
      STAGE_B(B, kk + 64, 1);
      LOAD_A(aB0, aB1, aB2, aB3, A, kk + 64);
      COMPUTE(Bs0, aA0, aA1, aA2, aA3);
      __syncthreads();
      STAGE_B(B, kk + 128, 0);
      LOAD_A(aA0, aA1, aA2, aA3, A, kk + 128);
      COMPUTE(Bs1, aB0, aB1, aB2, aB3);
      __syncthreads();
      kk += 128;
    }
    // kk == 1152 (in Bs0/aA); remaining steps 1152 and 1216
    STAGE_B(B, 1216, 1);
    LOAD_A(aB0, aB1, aB2, aB3, A, 1216);
    COMPUTE(Bs0, aA0, aA1, aA2, aA3);
    __syncthreads();
    if (b < 3) {  // cross-bin prefetch of next bin's kk=0
      STAGE_B(B + BHS, 0, 0);
      LOAD_A(aA0, aA1, aA2, aA3, A + AHS, 0);
    }
    COMPUTE(Bs1, aB0, aB1, aB2, aB3);
    __syncthreads();
    // fold this bin into the 8-rot accumulator (compile-time b)
#pragma unroll
    for (int rot = 0; rot < 8; ++rot) {
      const float cf = CF[b][rot], sf = SF[b][rot];
#pragma unroll
      for (int r = 0; r < 4; ++r) {
        oacc[rot][0][r] += cf * z00[r] + sf * z01[r];
        oacc[rot][1][r] += cf * z10[r] + sf * z11[r];
      }
    }
    A += AHS;
    B += BHS;
  }

  // epilogue: v=relu(oacc+40*bias[k,o]); lanes (tl, tl^1)=(k0,k1) of same o
  const int j = j0 + tl;  // 0..255
  const float bb = 40.0f * bias[((j & 1) << 7) | (j >> 1)];
  const int o = j >> 1;
#pragma unroll
  for (int rot = 0; rot < 8; ++rot)
#pragma unroll
    for (int mm = 0; mm < 2; ++mm)
#pragma unroll
      for (int r = 0; r < 4; ++r) {
        const int mrow = m0 + wm + mm * 16 + quad * 4 + r;
        float v = oacc[rot][mm][r] + bb;
        v = v > 0.f ? v : 0.f;
        const float vs = v + __shfl_xor(v, 1, 64);
        if (((lane & 1) == 0) && (mrow < N_PTS))
          out[(size_t)mrow * 1024 + rot * 128 + o] = vs;
      }
}

extern "C" void kernel_launch(void* const* d_in, const int* in_sizes, int n_in,
                              void* d_out, int out_size, void* d_ws,
                              size_t ws_size, hipStream_t stream) {
  const float* mesh = (const float*)d_in[0];    // (6000,128)
  const float* bary = (const float*)d_in[1];    // (6000,5,8,3,2)
  const float* kw = (const float*)d_in[2];      // (5,8,2,128,128)
  const float* bias = (const float*)d_in[3];    // (2,128)
  const float* interp = (const float*)d_in[4];  // (5,8,40)
  float* out = (float*)d_out;                   // (6000,8,128)

  bf16_t* Ahat = (bf16_t*)d_ws;                          // 61.44 MB
  bf16_t* Bhat = (bf16_t*)((char*)d_ws + 4 * AHS * 2);   // +5.24 MB

  prep_fft_kernel<<<SIG_BLOCKS + W2_BLOCKS, 256, 0, stream>>>(
      mesh, bary, kw, interp, Ahat, Bhat);
  gemm_fused_fft_kernel<<<768, 256, 0, stream>>>(Ahat, Bhat, bias, out);
}